// Round 3
// baseline (357.126 us; speedup 1.0000x reference)
//
#include <hip/hip_runtime.h>
#include <stdint.h>

#define HH 2048
#define WW 2048
#define HW (HH * WW)
#define N4 (HW / 4)
#define FB 512     // fine histogram bins over fixed [0,1)
#define G1 2048    // hist blocks, 256 threads: 2048*256*2 == N4 (exactly 2 iters/thread)
#define G3 2048    // main blocks, 256 threads: each thread one 2-row x 4-col strip

// ws uint32 layout — 519 words = 2076 B (PROVEN-SAFE; 17.4 KB faulted in a prior session):
// [0..511]   fine hist (u32 counts; stays raw — every main_k block derives the cdf in LDS)
// [512..517] acc floats: 0=recon_low 1=recon_eq 2=sum|dRg| 3=sumRg 4=sum|dL|e^-10|dRg| 5=sum L*e^-10Rg
// [518]      done counter

__device__ __forceinline__ float gray_pil(float r, float g, float b) {
    float qr = floorf(fminf(fmaxf(r, 0.f), 1.f) * 255.f);
    float qg = floorf(fminf(fmaxf(g, 0.f), 1.f) * 255.f);
    float qb = floorf(fminf(fmaxf(b, 0.f), 1.f) * 255.f);
    // all terms integers < 2^24: exact in fp32
    float s = floorf((qr * 19595.f + qg * 38470.f + qb * 7471.f + 32768.f) * (1.f / 65536.f));
    return s * (1.f / 255.f);
}

// ---------------- K1: fixed-range fine histogram of per-pixel channel max ----------------
// Copy-kernel shape: 2048 blocks x 256 threads (8 blocks/CU candidates, tail-covered).
__global__ __launch_bounds__(256, 8) void hist_k(const float* __restrict__ im, uint32_t* __restrict__ ctl) {
    __shared__ uint32_t lh[FB];
    int t = threadIdx.x;
    lh[t] = 0u;
    lh[t + 256] = 0u;
    __syncthreads();

    const float4* im4 = (const float4*)im;
    int tid = blockIdx.x * 256 + t;
#pragma unroll
    for (int k = 0; k < 2; ++k) {            // N4 == G1*256*2 exactly
        int i = tid + k * (G1 * 256);
        float4 a = im4[i], b = im4[i + N4], c = im4[i + 2 * N4];
        float m[4];
        m[0] = fmaxf(a.x, fmaxf(b.x, c.x));
        m[1] = fmaxf(a.y, fmaxf(b.y, c.y));
        m[2] = fmaxf(a.z, fmaxf(b.z, c.z));
        m[3] = fmaxf(a.w, fmaxf(b.w, c.w));
#pragma unroll
        for (int j = 0; j < 4; ++j) {
            int bin = (int)(m[j] * (float)FB);
            bin = bin < 0 ? 0 : (bin > FB - 1 ? FB - 1 : bin);
            atomicAdd(&lh[bin], 1u);
        }
    }
    __syncthreads();
    if (lh[t]) atomicAdd(&ctl[t], lh[t]);
    if (lh[t + 256]) atomicAdd(&ctl[t + 256], lh[t + 256]);
}

// ---------------- K2: fused main pass (per-block LDS cdf derivation) + finalize ----------------
__device__ __forceinline__ void px(float r0, float r1, float r2,
                                   float i0, float i1, float i2, float l,
                                   float& rgp, float& lp,
                                   const float* __restrict__ scdf, float gmin, float inv_dw,
                                   float& a0, float& a1, float& a2,
                                   float& a3, float& a4, float& a5) {
    a0 += fabsf(r0 * l - i0) + fabsf(r1 * l - i1) + fabsf(r2 * l - i2);
    float rmax = fmaxf(r0, fmaxf(r1, r2));
    float imax = fmaxf(i0, fmaxf(i1, i2));
    float t = (imax - gmin) * inv_dw;
    t = fmaxf(t, 0.f);
    int bi = (int)t;
    float eq;
    if (bi >= 255) eq = scdf[255];
    else {
        float fr = t - (float)bi;
        eq = scdf[bi] + fr * (scdf[bi + 1] - scdf[bi]);
    }
    a1 += fabsf(rmax - eq);
    float rg = gray_pil(r0, r1, r2);
    a3 += rg;
    a5 += l * __expf(-10.f * rg);
    float drg = fabsf(rg - rgp);
    a2 += drg;
    a4 += fabsf(l - lp) * __expf(-10.f * drg);
    rgp = rg;
    lp = l;
}

// 2048 blocks x 256 threads; global tid -> (col-group, 2-row strip):
//   c = tid & 511 -> columns c*4..c*4+3;  s = tid >> 9 -> rows 2s, 2s+1 (prologue row 2s-1).
// Each block first derives the 256-bin cdf from the global fine hist in LDS
// (integer arithmetic identical to the old cdf_k -> bit-identical scdf in every block).
__global__ __launch_bounds__(256, 4)
void main_k(const float* __restrict__ im, const float* __restrict__ R,
            const float* __restrict__ L, uint32_t* __restrict__ ctl,
            float* __restrict__ out) {
    __shared__ uint32_t sf[FB];
    __shared__ uint32_t sc[256];
    __shared__ float scdf[256];
    __shared__ uint32_t smm[2];
    __shared__ float red[6][4];
    int t = threadIdx.x;

    // ---- in-block cdf derivation (mirrors the retired cdf_k exactly) ----
    sf[t] = ctl[t];
    sf[t + 256] = ctl[t + 256];
    sc[t] = 0u;
    if (t == 0) { smm[0] = FB; smm[1] = 0u; }
    __syncthreads();
    if (sf[t]) { atomicMin(&smm[0], (uint32_t)t); atomicMax(&smm[1], (uint32_t)t); }
    if (sf[t + 256]) { atomicMin(&smm[0], (uint32_t)(t + 256)); atomicMax(&smm[1], (uint32_t)(t + 256)); }
    __syncthreads();
    float gmin = (float)smm[0] * (1.0f / (float)FB);         // left edge of first nonempty fine bin
    float gmax = (float)(smm[1] + 1u) * (1.0f / (float)FB);  // right edge of last nonempty fine bin
    float inv_dw = 256.0f / (gmax - gmin);
#pragma unroll
    for (int jj = 0; jj < 2; ++jj) {
        int j = t + jj * 256;
        uint32_t cnt = sf[j];
        if (cnt) {
            float c = ((float)j + 0.5f) * (1.0f / (float)FB);  // fine-bin center
            int q = (int)((c - gmin) * inv_dw);
            q = q < 0 ? 0 : (q > 255 ? 255 : q);
            atomicAdd(&sc[q], cnt);
        }
    }
    __syncthreads();
    // inclusive integer scan -> cdf (deterministic: bit-identical across blocks)
#pragma unroll
    for (int d = 1; d < 256; d <<= 1) {
        uint32_t v = (t >= d) ? sc[t - d] : 0u;
        __syncthreads();
        sc[t] += v;
        __syncthreads();
    }
    scdf[t] = (float)((double)sc[t] * (1.0 / (double)HW));
    __syncthreads();

    // ---- streaming main pass ----
    int tid = blockIdx.x * 256 + t;
    int w = (tid & 511) * 4;       // 4 adjacent columns per thread
    int h0 = (tid >> 9) * 2;       // 2-row strip per thread

    float a0 = 0.f, a1 = 0.f, a2 = 0.f, a3 = 0.f, a4 = 0.f, a5 = 0.f;
    float rgp[4], lp[4];
    if (h0 > 0) {
        int p = (h0 - 1) * WW + w;
        float4 Ra = *(const float4*)(R + p);
        float4 Rb = *(const float4*)(R + p + HW);
        float4 Rc = *(const float4*)(R + p + 2 * HW);
        float4 Lv = *(const float4*)(L + p);
        rgp[0] = gray_pil(Ra.x, Rb.x, Rc.x); lp[0] = Lv.x;
        rgp[1] = gray_pil(Ra.y, Rb.y, Rc.y); lp[1] = Lv.y;
        rgp[2] = gray_pil(Ra.z, Rb.z, Rc.z); lp[2] = Lv.z;
        rgp[3] = gray_pil(Ra.w, Rb.w, Rc.w); lp[3] = Lv.w;
    } else {
        rgp[0] = rgp[1] = rgp[2] = rgp[3] = 0.f;
        lp[0] = lp[1] = lp[2] = lp[3] = 0.f;
    }

#pragma unroll
    for (int h = h0; h < h0 + 2; ++h) {
        int p = h * WW + w;
        float4 r0 = *(const float4*)(R + p);
        float4 r1 = *(const float4*)(R + p + HW);
        float4 r2 = *(const float4*)(R + p + 2 * HW);
        float4 i0 = *(const float4*)(im + p);
        float4 i1 = *(const float4*)(im + p + HW);
        float4 i2 = *(const float4*)(im + p + 2 * HW);
        float4 lv = *(const float4*)(L + p);
        px(r0.x, r1.x, r2.x, i0.x, i1.x, i2.x, lv.x, rgp[0], lp[0], scdf, gmin, inv_dw, a0, a1, a2, a3, a4, a5);
        px(r0.y, r1.y, r2.y, i0.y, i1.y, i2.y, lv.y, rgp[1], lp[1], scdf, gmin, inv_dw, a0, a1, a2, a3, a4, a5);
        px(r0.z, r1.z, r2.z, i0.z, i1.z, i2.z, lv.z, rgp[2], lp[2], scdf, gmin, inv_dw, a0, a1, a2, a3, a4, a5);
        px(r0.w, r1.w, r2.w, i0.w, i1.w, i2.w, lv.w, rgp[3], lp[3], scdf, gmin, inv_dw, a0, a1, a2, a3, a4, a5);
    }
    if (h0 + 2 == HH) {  // boundary at h = 2048: |0 - x[2047]|
#pragma unroll
        for (int j = 0; j < 4; ++j) {
            a2 += rgp[j];
            a4 += lp[j] * __expf(-10.f * rgp[j]);
        }
    }

    for (int off = 32; off; off >>= 1) {
        a0 += __shfl_down(a0, off);
        a1 += __shfl_down(a1, off);
        a2 += __shfl_down(a2, off);
        a3 += __shfl_down(a3, off);
        a4 += __shfl_down(a4, off);
        a5 += __shfl_down(a5, off);
    }
    int lane = t & 63, wv = t >> 6;
    if (lane == 0) {
        red[0][wv] = a0; red[1][wv] = a1; red[2][wv] = a2;
        red[3][wv] = a3; red[4][wv] = a4; red[5][wv] = a5;
    }
    __syncthreads();
    if (t == 0) {
        float s0 = 0, s1 = 0, s2 = 0, s3 = 0, s4 = 0, s5 = 0;
        for (int k = 0; k < 4; k++) {
            s0 += red[0][k]; s1 += red[1][k]; s2 += red[2][k];
            s3 += red[3][k]; s4 += red[4][k]; s5 += red[5][k];
        }
        float* acc = (float*)(ctl + 512);
        atomicAdd(&acc[0], s0);
        atomicAdd(&acc[1], s1);
        atomicAdd(&acc[2], s2);
        atomicAdd(&acc[3], s3);
        atomicAdd(&acc[4], s4);
        atomicAdd(&acc[5], s5);
        __threadfence();
        uint32_t old = atomicAdd(&ctl[518], 1u);
        if (old == G3 - 1) {  // last block: all acc atomics happened-before
            float v0 = atomicAdd(&acc[0], 0.f);
            float v1 = atomicAdd(&acc[1], 0.f);
            float v2 = atomicAdd(&acc[2], 0.f);
            float v3 = atomicAdd(&acc[3], 0.f);
            float v4 = atomicAdd(&acc[4], 0.f);
            float v5 = atomicAdd(&acc[5], 0.f);
            float recon_low = v0 / (3.0f * (float)HW);
            float recon_eq = v1 / (float)HW;
            float denom = 2.0f * 2049.0f * 2050.0f;
            float r_smooth = (v2 + 2.f * v3) / denom;
            float ismooth = (v4 + 2.f * v5) / denom;
            out[0] = recon_low + 0.1f * ismooth + 0.1f * recon_eq + 0.01f * r_smooth;
        }
    }
}

extern "C" void kernel_launch(void* const* d_in, const int* in_sizes, int n_in,
                              void* d_out, int out_size, void* d_ws, size_t ws_size,
                              hipStream_t stream) {
    const float* im = (const float*)d_in[0];
    const float* R = (const float*)d_in[1];
    const float* L = (const float*)d_in[2];
    float* out = (float*)d_out;
    uint32_t* ctl = (uint32_t*)d_ws;

    hipMemsetAsync(d_ws, 0, 519 * 4, stream);  // graph-capturable memset node
    hipLaunchKernelGGL(hist_k, dim3(G1), dim3(256), 0, stream, im, ctl);
    hipLaunchKernelGGL(main_k, dim3(G3), dim3(256), 0, stream, im, R, L, ctl, out);
}

// Round 4
// 188.123 us; speedup vs baseline: 1.8984x; 1.8984x over previous
//
#include <hip/hip_runtime.h>
#include <stdint.h>

#define HH 2048
#define WW 2048
#define HW (HH * WW)
#define N4 (HW / 4)
#define FB 512      // fine histogram bins over fixed [0,1)
#define G1H 256     // hist blocks (1024 thr, 4 grid-stride iters: 256*1024*4 == N4)
#define G3M 256     // main blocks (1024 thr, 4-row strips: 512 strips x 512 col-groups)
#define STRIDE (G1H * 1024)

// ws uint32 layout (always-used region = 519 words, PROVEN-SAFE):
// [0..511]   fine hist (u32); AFTER hist_k last block: [0..255]=cdf(float), [256]=gmin, [257]=gmax
// [512..517] legacy acc floats (fallback finalize path only)
// [518]      SHARED done counter: hist_k adds G1H (last sees G1H-1), main_k adds G3M (last sees G1H+G3M-1)
// [520..2055] OPTIONAL per-block partials (256 blocks x 6 floats) — used only when ws_size allows (host-gated)

__device__ __forceinline__ float gray_pil(float r, float g, float b) {
    float qr = floorf(fminf(fmaxf(r, 0.f), 1.f) * 255.f);
    float qg = floorf(fminf(fmaxf(g, 0.f), 1.f) * 255.f);
    float qb = floorf(fminf(fmaxf(b, 0.f), 1.f) * 255.f);
    // all terms integers < 2^24: exact in fp32
    float s = floorf((qr * 19595.f + qg * 38470.f + qb * 7471.f + 32768.f) * (1.f / 65536.f));
    return s * (1.f / 255.f);
}

// ---------------- K1: fine histogram + (last block) cdf derivation ----------------
__global__ __launch_bounds__(1024, 4)
void hist_k(const float* __restrict__ im, uint32_t* __restrict__ ctl) {
    __shared__ uint32_t lh[FB];
    __shared__ uint32_t sc[256];
    __shared__ uint32_t smm[2];
    __shared__ uint32_t lastf;
    int t = threadIdx.x;
    if (t < FB) lh[t] = 0u;
    __syncthreads();

    const float4* im4 = (const float4*)im;
    int tid = blockIdx.x * 1024 + t;
    // hoisted loads: 12 independent float4 in flight before any compute
    float4 A0 = im4[tid],              B0 = im4[tid + N4],              C0 = im4[tid + 2 * N4];
    float4 A1 = im4[tid + STRIDE],     B1 = im4[tid + STRIDE + N4],     C1 = im4[tid + STRIDE + 2 * N4];
    float4 A2 = im4[tid + 2 * STRIDE], B2 = im4[tid + 2 * STRIDE + N4], C2 = im4[tid + 2 * STRIDE + 2 * N4];
    float4 A3 = im4[tid + 3 * STRIDE], B3 = im4[tid + 3 * STRIDE + N4], C3 = im4[tid + 3 * STRIDE + 2 * N4];

#define HBIN(a, b, c) { \
        float m0 = fmaxf(a.x, fmaxf(b.x, c.x)); \
        float m1 = fmaxf(a.y, fmaxf(b.y, c.y)); \
        float m2 = fmaxf(a.z, fmaxf(b.z, c.z)); \
        float m3 = fmaxf(a.w, fmaxf(b.w, c.w)); \
        int b0 = (int)(m0 * (float)FB); b0 = b0 < 0 ? 0 : (b0 > FB - 1 ? FB - 1 : b0); \
        int b1 = (int)(m1 * (float)FB); b1 = b1 < 0 ? 0 : (b1 > FB - 1 ? FB - 1 : b1); \
        int b2 = (int)(m2 * (float)FB); b2 = b2 < 0 ? 0 : (b2 > FB - 1 ? FB - 1 : b2); \
        int b3 = (int)(m3 * (float)FB); b3 = b3 < 0 ? 0 : (b3 > FB - 1 ? FB - 1 : b3); \
        atomicAdd(&lh[b0], 1u); atomicAdd(&lh[b1], 1u); \
        atomicAdd(&lh[b2], 1u); atomicAdd(&lh[b3], 1u); }
    HBIN(A0, B0, C0)
    HBIN(A1, B1, C1)
    HBIN(A2, B2, C2)
    HBIN(A3, B3, C3)
#undef HBIN

    __syncthreads();
    if (t < FB && lh[t]) atomicAdd(&ctl[t], lh[t]);
    __syncthreads();
    if (t == 0) {
        __threadfence();
        lastf = (atomicAdd(&ctl[518], 1u) == G1H - 1) ? 1u : 0u;
    }
    __syncthreads();
    if (!lastf) return;

    // ---- last block only: derive 256-bin cdf (exact numerics of the retired cdf_k) ----
    if (t < FB) lh[t] = atomicAdd(&ctl[t], 0u);   // device-scope read: sees all flush atomics
    if (t < 256) sc[t] = 0u;
    if (t == 0) { smm[0] = FB; smm[1] = 0u; }
    __syncthreads();
    if (t < FB && lh[t]) { atomicMin(&smm[0], (uint32_t)t); atomicMax(&smm[1], (uint32_t)t); }
    __syncthreads();
    float gmin = (float)smm[0] * (1.0f / (float)FB);         // left edge of first nonempty fine bin
    float gmax = (float)(smm[1] + 1u) * (1.0f / (float)FB);  // right edge of last nonempty fine bin
    float inv_dw = 256.0f / (gmax - gmin);
    if (t < FB && lh[t]) {
        float c = ((float)t + 0.5f) * (1.0f / (float)FB);    // fine-bin center
        int q = (int)((c - gmin) * inv_dw);
        q = q < 0 ? 0 : (q > 255 ? 255 : q);
        atomicAdd(&sc[q], lh[t]);
    }
    __syncthreads();
    // inclusive integer scan -> cdf (barriers unconditional for all 1024 threads)
    for (int d = 1; d < 256; d <<= 1) {
        uint32_t v = (t < 256 && t >= d) ? sc[t - d] : 0u;
        __syncthreads();
        if (t < 256) sc[t] += v;
        __syncthreads();
    }
    float* cf = (float*)ctl;
    if (t < 256) cf[t] = (float)((double)sc[t] * (1.0 / (double)HW));
    if (t == 0) { cf[256] = gmin; cf[257] = gmax; }
}

// ---------------- K2: fused main pass + finalize ----------------
__device__ __forceinline__ void px(float r0, float r1, float r2,
                                   float i0, float i1, float i2, float l,
                                   float& rgp, float& lp,
                                   const float* __restrict__ scdf, float gmin, float inv_dw,
                                   float& a0, float& a1, float& a2,
                                   float& a3, float& a4, float& a5) {
    a0 += fabsf(r0 * l - i0) + fabsf(r1 * l - i1) + fabsf(r2 * l - i2);
    float rmax = fmaxf(r0, fmaxf(r1, r2));
    float imax = fmaxf(i0, fmaxf(i1, i2));
    float t = (imax - gmin) * inv_dw;
    t = fmaxf(t, 0.f);
    int bi = (int)t;
    float eq;
    if (bi >= 255) eq = scdf[255];
    else {
        float fr = t - (float)bi;
        eq = scdf[bi] + fr * (scdf[bi + 1] - scdf[bi]);
    }
    a1 += fabsf(rmax - eq);
    float rg = gray_pil(r0, r1, r2);
    a3 += rg;
    a5 += l * __expf(-10.f * rg);
    float drg = fabsf(rg - rgp);
    a2 += drg;
    a4 += fabsf(l - lp) * __expf(-10.f * drg);
    rgp = rg;
    lp = l;
}

// 256 blocks x 1024 threads (1 block/CU, all-resident). Thread t of block b:
//   tid = b*1024+t; columns (tid&511)*4..+3; rows h0..h0+3 where h0 = (tid>>9)*4.
// 4-row strips cut the prologue-row re-read redundancy to 12.5% and give the
// scheduler 4 unrolled iterations of independent loads to hoist (VGPR cap 128).
__global__ __launch_bounds__(1024, 4)
void main_k(const float* __restrict__ im, const float* __restrict__ R,
            const float* __restrict__ L, uint32_t* __restrict__ ctl,
            float* __restrict__ part, int use_part,
            float* __restrict__ out) {
    __shared__ float scdf[256];
    __shared__ float red[6][16];
    __shared__ uint32_t lastf;
    int t = threadIdx.x;

    const float* cf = (const float*)ctl;
    if (t < 256) scdf[t] = cf[t];
    float gmin = cf[256];
    float gmax = cf[257];
    float inv_dw = 256.0f / (gmax - gmin);
    __syncthreads();

    int tid = blockIdx.x * 1024 + t;
    int w = (tid & 511) * 4;       // 4 adjacent columns per thread
    int h0 = (tid >> 9) * 4;       // 4-row strip per thread

    float a0 = 0.f, a1 = 0.f, a2 = 0.f, a3 = 0.f, a4 = 0.f, a5 = 0.f;
    float rgp[4], lp[4];
    if (h0 > 0) {
        int p = (h0 - 1) * WW + w;
        float4 Ra = *(const float4*)(R + p);
        float4 Rb = *(const float4*)(R + p + HW);
        float4 Rc = *(const float4*)(R + p + 2 * HW);
        float4 Lv = *(const float4*)(L + p);
        rgp[0] = gray_pil(Ra.x, Rb.x, Rc.x); lp[0] = Lv.x;
        rgp[1] = gray_pil(Ra.y, Rb.y, Rc.y); lp[1] = Lv.y;
        rgp[2] = gray_pil(Ra.z, Rb.z, Rc.z); lp[2] = Lv.z;
        rgp[3] = gray_pil(Ra.w, Rb.w, Rc.w); lp[3] = Lv.w;
    } else {
        rgp[0] = rgp[1] = rgp[2] = rgp[3] = 0.f;
        lp[0] = lp[1] = lp[2] = lp[3] = 0.f;
    }

#pragma unroll
    for (int hh = 0; hh < 4; ++hh) {
        int p = (h0 + hh) * WW + w;
        float4 r0 = *(const float4*)(R + p);
        float4 r1 = *(const float4*)(R + p + HW);
        float4 r2 = *(const float4*)(R + p + 2 * HW);
        float4 i0 = *(const float4*)(im + p);
        float4 i1 = *(const float4*)(im + p + HW);
        float4 i2 = *(const float4*)(im + p + 2 * HW);
        float4 lv = *(const float4*)(L + p);
        px(r0.x, r1.x, r2.x, i0.x, i1.x, i2.x, lv.x, rgp[0], lp[0], scdf, gmin, inv_dw, a0, a1, a2, a3, a4, a5);
        px(r0.y, r1.y, r2.y, i0.y, i1.y, i2.y, lv.y, rgp[1], lp[1], scdf, gmin, inv_dw, a0, a1, a2, a3, a4, a5);
        px(r0.z, r1.z, r2.z, i0.z, i1.z, i2.z, lv.z, rgp[2], lp[2], scdf, gmin, inv_dw, a0, a1, a2, a3, a4, a5);
        px(r0.w, r1.w, r2.w, i0.w, i1.w, i2.w, lv.w, rgp[3], lp[3], scdf, gmin, inv_dw, a0, a1, a2, a3, a4, a5);
    }
    if (h0 + 4 == HH) {  // boundary at h = 2048: |0 - x[2047]|
#pragma unroll
        for (int j = 0; j < 4; ++j) {
            a2 += rgp[j];
            a4 += lp[j] * __expf(-10.f * rgp[j]);
        }
    }

    for (int off = 32; off; off >>= 1) {
        a0 += __shfl_down(a0, off);
        a1 += __shfl_down(a1, off);
        a2 += __shfl_down(a2, off);
        a3 += __shfl_down(a3, off);
        a4 += __shfl_down(a4, off);
        a5 += __shfl_down(a5, off);
    }
    int lane = t & 63, wv = t >> 6;
    if (lane == 0) {
        red[0][wv] = a0; red[1][wv] = a1; red[2][wv] = a2;
        red[3][wv] = a3; red[4][wv] = a4; red[5][wv] = a5;
    }
    __syncthreads();
    if (t == 0) {
        float s0 = 0, s1 = 0, s2 = 0, s3 = 0, s4 = 0, s5 = 0;
        for (int k = 0; k < 16; k++) {
            s0 += red[0][k]; s1 += red[1][k]; s2 += red[2][k];
            s3 += red[3][k]; s4 += red[4][k]; s5 += red[5][k];
        }
        if (use_part) {
            // chain-free: distinct slot per block, atomicExch pushes to coherence point
            float* pp = part + blockIdx.x * 6;
            atomicExch(&pp[0], s0); atomicExch(&pp[1], s1); atomicExch(&pp[2], s2);
            atomicExch(&pp[3], s3); atomicExch(&pp[4], s4); atomicExch(&pp[5], s5);
        } else {
            float* acc = (float*)(ctl + 512);
            atomicAdd(&acc[0], s0); atomicAdd(&acc[1], s1); atomicAdd(&acc[2], s2);
            atomicAdd(&acc[3], s3); atomicAdd(&acc[4], s4); atomicAdd(&acc[5], s5);
        }
        __threadfence();
        lastf = (atomicAdd(&ctl[518], 1u) == (uint32_t)(G1H + G3M - 1)) ? 1u : 0u;
    }
    __syncthreads();
    if (!lastf) return;

    // ---- last block: final combine ----
    if (use_part) {
        float s0 = 0.f, s1 = 0.f, s2 = 0.f, s3 = 0.f, s4 = 0.f, s5 = 0.f;
        if (t < G3M) {
            float* pp = part + t * 6;
            s0 = atomicAdd(&pp[0], 0.f); s1 = atomicAdd(&pp[1], 0.f); s2 = atomicAdd(&pp[2], 0.f);
            s3 = atomicAdd(&pp[3], 0.f); s4 = atomicAdd(&pp[4], 0.f); s5 = atomicAdd(&pp[5], 0.f);
        }
        for (int off = 32; off; off >>= 1) {
            s0 += __shfl_down(s0, off);
            s1 += __shfl_down(s1, off);
            s2 += __shfl_down(s2, off);
            s3 += __shfl_down(s3, off);
            s4 += __shfl_down(s4, off);
            s5 += __shfl_down(s5, off);
        }
        if (lane == 0) {
            red[0][wv] = s0; red[1][wv] = s1; red[2][wv] = s2;
            red[3][wv] = s3; red[4][wv] = s4; red[5][wv] = s5;
        }
        __syncthreads();
        if (t == 0) {
            float v0 = 0, v1 = 0, v2 = 0, v3 = 0, v4 = 0, v5 = 0;
            for (int k = 0; k < 16; k++) {
                v0 += red[0][k]; v1 += red[1][k]; v2 += red[2][k];
                v3 += red[3][k]; v4 += red[4][k]; v5 += red[5][k];
            }
            float recon_low = v0 / (3.0f * (float)HW);
            float recon_eq = v1 / (float)HW;
            float denom = 2.0f * 2049.0f * 2050.0f;
            float r_smooth = (v2 + 2.f * v3) / denom;
            float ismooth = (v4 + 2.f * v5) / denom;
            out[0] = recon_low + 0.1f * ismooth + 0.1f * recon_eq + 0.01f * r_smooth;
        }
    } else {
        if (t == 0) {
            float* acc = (float*)(ctl + 512);
            float v0 = atomicAdd(&acc[0], 0.f);
            float v1 = atomicAdd(&acc[1], 0.f);
            float v2 = atomicAdd(&acc[2], 0.f);
            float v3 = atomicAdd(&acc[3], 0.f);
            float v4 = atomicAdd(&acc[4], 0.f);
            float v5 = atomicAdd(&acc[5], 0.f);
            float recon_low = v0 / (3.0f * (float)HW);
            float recon_eq = v1 / (float)HW;
            float denom = 2.0f * 2049.0f * 2050.0f;
            float r_smooth = (v2 + 2.f * v3) / denom;
            float ismooth = (v4 + 2.f * v5) / denom;
            out[0] = recon_low + 0.1f * ismooth + 0.1f * recon_eq + 0.01f * r_smooth;
        }
    }
}

extern "C" void kernel_launch(void* const* d_in, const int* in_sizes, int n_in,
                              void* d_out, int out_size, void* d_ws, size_t ws_size,
                              hipStream_t stream) {
    const float* im = (const float*)d_in[0];
    const float* R = (const float*)d_in[1];
    const float* L = (const float*)d_in[2];
    float* out = (float*)d_out;
    uint32_t* ctl = (uint32_t*)d_ws;

    // partials region: words [520 .. 520 + 6*G3M) = 8224 B total; gate on actual ws_size
    int use_part = (ws_size >= (size_t)((520 + 6 * G3M) * 4 + 32)) ? 1 : 0;
    float* part = (float*)(ctl + 520);

    hipMemsetAsync(d_ws, 0, 519 * 4, stream);  // graph-capturable memset node
    hipLaunchKernelGGL(hist_k, dim3(G1H), dim3(1024), 0, stream, im, ctl);
    hipLaunchKernelGGL(main_k, dim3(G3M), dim3(1024), 0, stream, im, R, L, ctl, part, use_part, out);
}